// Round 11
// baseline (166.189 us; speedup 1.0000x reference)
//
#include <hip/hip_runtime.h>

typedef __bf16 bf16_t;
typedef __bf16 bf16x8 __attribute__((ext_vector_type(8)));
typedef __bf16 bf16x4 __attribute__((ext_vector_type(4)));
typedef float f32x4 __attribute__((ext_vector_type(4)));

#define M_DIM 4096
#define N_DIM 4096   // 2 * OUT_FEATURES
#define K_DIM 4096   // 2 * IN_FEATURES
#define OUTF 2048
#define INF 2048
#define LDK 4096
#define NT32 128     // K-tiles of 32

// ---------------------------------------------------------------------------
// Pack kernel: build bf16 A = [x_re | x_im]  (4096 x 4096)
//              and  bf16 B = [[w_re, -w_im]; [w_im, w_re]] (4096 x 4096)
// ---------------------------------------------------------------------------
__global__ __launch_bounds__(256) void pack_ab(
    const float* __restrict__ xre, const float* __restrict__ xim,
    const float* __restrict__ wre, const float* __restrict__ wim,
    bf16_t* __restrict__ Abf, bf16_t* __restrict__ Bbf)
{
  size_t gid = (size_t)blockIdx.x * 256 + threadIdx.x;
  size_t e8  = gid * 8;
  const size_t MAT = (size_t)4096 * 4096;
  bool isB = e8 >= MAT;
  size_t e = isB ? (e8 - MAT) : e8;
  int row = (int)(e >> 12);
  int k   = (int)(e & 4095);

  const float* src;
  float s = 1.0f;
  if (!isB) {
    src = (k < INF) ? (xre + (size_t)row * INF + k)
                    : (xim + (size_t)row * INF + (k - INF));
  } else {
    if (row < OUTF) {
      if (k < INF) { src = wre + (size_t)row * INF + k; }
      else         { src = wim + (size_t)row * INF + (k - INF); s = -1.0f; }
    } else {
      int o = row - OUTF;
      src = (k < INF) ? (wim + (size_t)o * INF + k)
                      : (wre + (size_t)o * INF + (k - INF));
    }
  }
  const float4* p = reinterpret_cast<const float4*>(src);
  float4 f0 = p[0];
  float4 f1 = p[1];
  bf16x8 v;
  v[0] = (bf16_t)(f0.x * s); v[1] = (bf16_t)(f0.y * s);
  v[2] = (bf16_t)(f0.z * s); v[3] = (bf16_t)(f0.w * s);
  v[4] = (bf16_t)(f1.x * s); v[5] = (bf16_t)(f1.y * s);
  v[6] = (bf16_t)(f1.z * s); v[7] = (bf16_t)(f1.w * s);
  bf16_t* dst = (isB ? Bbf : Abf) + e;
  *reinterpret_cast<bf16x8*>(dst) = v;
}

// ---------------------------------------------------------------------------
__device__ __forceinline__ void gld_lds16(const void* g, void* l) {
  __builtin_amdgcn_global_load_lds(
      (const __attribute__((address_space(1))) void*)g,
      (__attribute__((address_space(3))) void*)l,
      16, 0, 0);
}

// ---------------------------------------------------------------------------
// 128x256 GEMM, 2 blocks/CU (R11).
//   Diagnosis R3-R10: 256-sq = 1 block/CU; barrier-locked waves -> CU-global
//   read/MFMA ping-pong no intra-block schedule can fix (7 nulls). Fix:
//   smaller tile, SAME per-CU LDS read volume, 2 independent blocks/CU ->
//   one block's MFMA covers the other's read-drain (m114 mechanism).
//   Tile 128x256, BK=32, 4 waves (2Mx2N, per-wave 64x128), grid 512,
//   LDS 2 x 24 KiB. BK=32 row stride 64B: fragment reads are conflict-free
//   with NO swizzle (8 lanes/16B-slot x 8 slots = uniform 8/bank).
//   Schedule per K-tile: reads(c) -> MFMA -> BAR1 (readers of c done) ->
//   STAGE(t+2 -> c) -> vmcnt(6) (drains t+1's stages, t+2's stay in
//   flight, ~1 full tile of cover) -> BAR2.
// ---------------------------------------------------------------------------
__global__ __launch_bounds__(256, 2) void gemm128x256(
    const bf16_t* __restrict__ A, const bf16_t* __restrict__ B,
    float* __restrict__ out)
{
  // LDS buffer c at c*24576: A [128][32] (8 KB) | B [256][32] (16 KB)
  __shared__ alignas(16) bf16_t lds[2 * 12288];
  char* Lb = (char*)lds;

  const int tid  = threadIdx.x;
  const int lane = tid & 63;
  const int wid  = tid >> 6;    // 0..3
  const int wm   = wid >> 1;    // 0..1 -> rows wm*64
  const int wn   = wid & 1;     // 0..1 -> cols wn*128
  const int lr   = lane & 15;
  const int kg   = (lane >> 4) * 16;   // 16B slot in 64B row

  int bid = blockIdx.x;
  int swz = (bid & 7) * 64 + (bid >> 3);   // 512 blocks, XCD chunks of 64
  const int bm = swz >> 4;    // 0..31 (128 rows)
  const int bn = swz & 15;    // 0..15 (256 cols)

  // Staging sources (linear LDS dest, no swizzle):
  // load j writes LDS bytes j*4096 + tid*16 -> row = j*64 + (tid>>2),
  // col byte = (tid&3)*16 -> col elem = (tid&3)*8.
  const bf16_t* Asrc = A + (size_t)(bm * 128 + (tid >> 2)) * LDK + (tid & 3) * 8;
  const bf16_t* Bsrc = B + (size_t)(bn * 256 + (tid >> 2)) * LDK + (tid & 3) * 8;
  const int dst16 = tid * 16;

#define STAGE(t, c) do {                                                       \
    _Pragma("unroll")                                                          \
    for (int j_ = 0; j_ < 2; ++j_)                                             \
      gld_lds16(Asrc + (size_t)j_ * 64 * LDK + (t) * 32,                       \
                Lb + (c) * 24576 + j_ * 4096 + dst16);                         \
    _Pragma("unroll")                                                          \
    for (int j_ = 0; j_ < 4; ++j_)                                             \
      gld_lds16(Bsrc + (size_t)j_ * 64 * LDK + (t) * 32,                       \
                Lb + (c) * 24576 + 8192 + j_ * 4096 + dst16);                  \
  } while (0)
#define RD_A(c, m)                                                             \
  (*(const bf16x8*)(Lb + (c) * 24576 + (wm * 64 + (m) * 16 + lr) * 64 + kg))
#define RD_B(c, n)                                                             \
  (*(const bf16x8*)(Lb + (c) * 24576 + 8192 +                                  \
                    (wn * 128 + (n) * 16 + lr) * 64 + kg))
#define BAR()   __builtin_amdgcn_s_barrier()

  f32x4 acc[4][8];
#pragma unroll
  for (int m = 0; m < 4; ++m)
#pragma unroll
    for (int n = 0; n < 8; ++n)
      acc[m][n] = (f32x4){0.f, 0.f, 0.f, 0.f};

  // Prologue: tile0 -> buf0, tile1 -> buf1 (12 loads).
  // vmcnt(6): tile0 resident, tile1's 6 in flight.
  STAGE(0, 0);
  STAGE(1, 1);
  asm volatile("s_waitcnt vmcnt(6)" ::: "memory");
  BAR();

  for (int t = 0; t < NT32; ++t) {
    const int c = t & 1;
    bf16x8 aF[4], bF[8];
#pragma unroll
    for (int m = 0; m < 4; ++m) aF[m] = RD_A(c, m);
#pragma unroll
    for (int n = 0; n < 8; ++n) bF[n] = RD_B(c, n);
    // compiler inserts exact lgkmcnt before first dependent MFMA
    __builtin_amdgcn_s_setprio(1);
#pragma unroll
    for (int m = 0; m < 4; ++m)
#pragma unroll
      for (int n = 0; n < 8; ++n)
        acc[m][n] = __builtin_amdgcn_mfma_f32_16x16x32_bf16(aF[m], bF[n],
                                                            acc[m][n], 0, 0, 0);
    __builtin_amdgcn_s_setprio(0);
    BAR();   // BAR1: all waves' reads of buf c complete -> re-stage safe

    if (t + 2 < NT32) {
      STAGE(t + 2, c);
      // outstanding: t+1's 6 + t+2's 6 -> drain t+1's only
      asm volatile("s_waitcnt vmcnt(6)" ::: "memory");
    } else {
      asm volatile("s_waitcnt vmcnt(0)" ::: "memory");
    }
    BAR();   // BAR2: next tile's buffer globally resident
  }

  // Epilogue: C/D layout col=lane&15, row=(lane>>4)*4+j (verified m89/m91)
  const size_t imOff = (size_t)M_DIM * OUTF;
  const int fq = (lane >> 4) * 4;
  const bool isIm = (bn * 256) >= OUTF;          // bn>=8 -> imaginary half
  float* obase = out + (isIm ? imOff : 0);
  const int colBase = bn * 256 - (isIm ? OUTF : 0) + wn * 128;
#pragma unroll
  for (int m = 0; m < 4; ++m) {
    int gr = bm * 128 + wm * 64 + m * 16 + fq;
#pragma unroll
    for (int n = 0; n < 8; ++n) {
      int gc = colBase + n * 16 + lr;
#pragma unroll
      for (int j = 0; j < 4; ++j)
        obase[(size_t)(gr + j) * OUTF + gc] = acc[m][n][j];
    }
  }
#undef STAGE
#undef RD_A
#undef RD_B
#undef BAR
}

// ---------------------------------------------------------------------------
// Fallback: fused fp32->bf16 conversion + GEMM (no workspace needed).
// ---------------------------------------------------------------------------
__global__ __launch_bounds__(256) void gemm_fused(
    const float* __restrict__ xre, const float* __restrict__ xim,
    const float* __restrict__ wre, const float* __restrict__ wim,
    float* __restrict__ out)
{
  __shared__ alignas(16) bf16_t As[128 * 40];
  __shared__ alignas(16) bf16_t Bs[128 * 40];

  int tid = threadIdx.x;
  int bid = blockIdx.x;
  int swz = (bid & 7) * 128 + (bid >> 3);
  int bm = swz >> 5;
  int bn = swz & 31;

  int lane = tid & 63;
  int w    = tid >> 6;
  int wm   = (w >> 1) * 64;
  int wn   = (w & 1) * 64;
  int lr   = lane & 15;
  int lk   = (lane >> 4) * 8;

  f32x4 acc[4][4];
#pragma unroll
  for (int m = 0; m < 4; ++m)
#pragma unroll
    for (int n = 0; n < 4; ++n)
      acc[m][n] = (f32x4){0.f, 0.f, 0.f, 0.f};

  int srow = tid >> 3;
  int scol = (tid & 7) * 4;

  bool nIm  = (bn * 128) >= OUTF;
  int nbase = nIm ? (bn * 128 - OUTF) : (bn * 128);

  for (int kt = 0; kt < K_DIM / 32; ++kt) {
    int k0 = kt * 32;
    bool kHi = (k0 >= INF);
    int kk = kHi ? (k0 - INF) : k0;

    const float* Asrc = (kHi ? xim : xre) + (size_t)(bm * 128) * INF + kk;
    const float* Bsrc;
    float s = 1.0f;
    if (!nIm) { if (!kHi) { Bsrc = wre; } else { Bsrc = wim; s = -1.0f; } }
    else      { Bsrc = kHi ? wre : wim; }
    Bsrc += (size_t)nbase * INF + kk;

    float4 av[4], bv[4];
#pragma unroll
    for (int i = 0; i < 4; ++i) {
      av[i] = *reinterpret_cast<const float4*>(Asrc + (size_t)(srow + i * 32) * INF + scol);
      bv[i] = *reinterpret_cast<const float4*>(Bsrc + (size_t)(srow + i * 32) * INF + scol);
    }
    __syncthreads();
#pragma unroll
    for (int i = 0; i < 4; ++i) {
      bf16x4 a4, b4;
      a4[0] = (bf16_t)av[i].x; a4[1] = (bf16_t)av[i].y;
      a4[2] = (bf16_t)av[i].z; a4[3] = (bf16_t)av[i].w;
      b4[0] = (bf16_t)(bv[i].x * s); b4[1] = (bf16_t)(bv[i].y * s);
      b4[2] = (bf16_t)(bv[i].z * s); b4[3] = (bf16_t)(bv[i].w * s);
      *reinterpret_cast<bf16x4*>(&As[(srow + i * 32) * 40 + scol]) = a4;
      *reinterpret_cast<bf16x4*>(&Bs[(srow + i * 32) * 40 + scol]) = b4;
    }
    __syncthreads();

    bf16x8 a[4], b[4];
#pragma unroll
    for (int m = 0; m < 4; ++m)
      a[m] = *reinterpret_cast<const bf16x8*>(&As[(wm + m * 16 + lr) * 40 + lk]);
#pragma unroll
    for (int n = 0; n < 4; ++n)
      b[n] = *reinterpret_cast<const bf16x8*>(&Bs[(wn + n * 16 + lr) * 40 + lk]);
#pragma unroll
    for (int m = 0; m < 4; ++m)
#pragma unroll
      for (int n = 0; n < 4; ++n)
        acc[m][n] = __builtin_amdgcn_mfma_f32_16x16x32_bf16(a[m], b[n], acc[m][n], 0, 0, 0);
  }
  __syncthreads();

  const size_t imOff = (size_t)M_DIM * OUTF;
  int fq = (lane >> 4) * 4;
#pragma unroll
  for (int m = 0; m < 4; ++m) {
    int gr = bm * 128 + wm + m * 16 + fq;
#pragma unroll
    for (int n = 0; n < 4; ++n) {
      int gc = bn * 128 + wn + n * 16 + lr;
      float* dst = (gc < OUTF) ? (out + (size_t)gr * OUTF + gc)
                               : (out + imOff + (size_t)gr * OUTF + (gc - OUTF));
#pragma unroll
      for (int j = 0; j < 4; ++j)
        dst[(size_t)j * OUTF] = acc[m][n][j];
    }
  }
}

// ---------------------------------------------------------------------------
extern "C" void kernel_launch(void* const* d_in, const int* in_sizes, int n_in,
                              void* d_out, int out_size, void* d_ws, size_t ws_size,
                              hipStream_t stream) {
  const float* xre = (const float*)d_in[0];
  const float* xim = (const float*)d_in[1];
  const float* wre = (const float*)d_in[2];
  const float* wim = (const float*)d_in[3];
  float* out = (float*)d_out;

  const size_t need = (size_t)2 * 4096 * 4096 * sizeof(bf16_t);  // 64 MiB
  if (ws_size >= need) {
    bf16_t* Abf = (bf16_t*)d_ws;
    bf16_t* Bbf = Abf + (size_t)4096 * 4096;
    hipLaunchKernelGGL(pack_ab, dim3(16384), dim3(256), 0, stream,
                       xre, xim, wre, wim, Abf, Bbf);
    hipLaunchKernelGGL(gemm128x256, dim3(512), dim3(256), 0, stream,
                       Abf, Bbf, out);
  } else {
    hipLaunchKernelGGL(gemm_fused, dim3(1024), dim3(256), 0, stream,
                       xre, xim, wre, wim, out);
  }
}